// Round 1
// baseline (194.507 us; speedup 1.0000x reference)
//
#include <hip/hip_runtime.h>
#include <math.h>

// BondOrderInteraction: e_src = NF@W_src + b_src, e_dst = NF@W_dst  [N,4]
// params = exp(e_src[src] + e_dst[dst]) per edge; pair potential w/ cutoff;
// segment-sum into dst nodes.
//
// Inputs (setup_inputs order):
//  0 node_features [N,256] f32
//  1 bond_order    [E]     f32
//  2 bondlength    [E]     f32
//  3 src           [E]     i32
//  4 dst           [E]     i32
//  5 W_src         [256,4] f32
//  6 b_src         [4]     f32
//  7 W_dst         [256,4] f32
// Output: [N] f32

#define F_IN 256

// ---------------- kernel 1: per-node 4-vector projections -------------------
// One wave (64 lanes) per node: lane i loads float4 at feature offset i*4
// (contiguous, coalesced 1 KB per wave), accumulates partial dot products for
// 8 outputs (4 src-proj + 4 dst-proj), then a 6-level butterfly reduce.
__global__ __launch_bounds__(256) void node_proj_kernel(
    const float* __restrict__ nf,
    const float* __restrict__ Wsrc,
    const float* __restrict__ bsrc,
    const float* __restrict__ Wdst,
    float* __restrict__ esrc,
    float* __restrict__ edst,
    int n_nodes) {
  const int gtid = blockIdx.x * blockDim.x + threadIdx.x;
  const int node = gtid >> 6;
  const int lane = threadIdx.x & 63;
  if (node >= n_nodes) return;

  const float4 f =
      *reinterpret_cast<const float4*>(nf + (size_t)node * F_IN + lane * 4);

  float acc[8] = {0.f, 0.f, 0.f, 0.f, 0.f, 0.f, 0.f, 0.f};
#pragma unroll
  for (int t = 0; t < 4; ++t) {
    const float fv = (&f.x)[t];
    const int j = lane * 4 + t;  // feature index
    const float4 ws = *reinterpret_cast<const float4*>(Wsrc + j * 4);
    const float4 wd = *reinterpret_cast<const float4*>(Wdst + j * 4);
    acc[0] += fv * ws.x; acc[1] += fv * ws.y;
    acc[2] += fv * ws.z; acc[3] += fv * ws.w;
    acc[4] += fv * wd.x; acc[5] += fv * wd.y;
    acc[6] += fv * wd.z; acc[7] += fv * wd.w;
  }

#pragma unroll
  for (int off = 32; off >= 1; off >>= 1) {
#pragma unroll
    for (int k = 0; k < 8; ++k) acc[k] += __shfl_xor(acc[k], off, 64);
  }

  if (lane == 0) {
    float4 es = {acc[0] + bsrc[0], acc[1] + bsrc[1],
                 acc[2] + bsrc[2], acc[3] + bsrc[3]};
    float4 ed = {acc[4], acc[5], acc[6], acc[7]};
    *reinterpret_cast<float4*>(esrc + (size_t)node * 4) = es;
    *reinterpret_cast<float4*>(edst + (size_t)node * 4) = ed;
  }
}

// ---------------- kernel 2: per-edge potential + scatter-add ----------------
// cutoff(r): 1 for r<3.8; 0 for r>4.0; 0.5-0.5*sin(pi*(r-3.9)/0.2) between.
__global__ __launch_bounds__(256) void edge_kernel(
    const float* __restrict__ bond_order,
    const float* __restrict__ bondlength,
    const int* __restrict__ src,
    const int* __restrict__ dst,
    const float* __restrict__ esrc,
    const float* __restrict__ edst,
    float* __restrict__ out,
    int n_edges) {
  const int e = blockIdx.x * blockDim.x + threadIdx.x;
  if (e >= n_edges) return;

  const float r = bondlength[e];
  if (r >= 4.0f) return;  // cutoff == 0 (equals reference at the boundary)

  const int s = src[e];
  const int d = dst[e];
  const float4 es = *reinterpret_cast<const float4*>(esrc + (size_t)s * 4);
  const float4 ed = *reinterpret_cast<const float4*>(edst + (size_t)d * 4);

  const float p0 = expf(es.x + ed.x);
  const float p1 = expf(es.y + ed.y);
  const float p2 = expf(es.z + ed.z);
  const float p3 = expf(es.w + ed.w);

  const float f_rep = p0 * expf(-p1 * r);
  const float f_att = p2 * expf(-p3 * r);

  float c = 1.0f;
  if (r > 3.8f) {
    c = 0.5f - 0.5f * sinf((float)M_PI * (r - 3.9f) * 5.0f);  // /0.2 == *5
  }

  const float V = c * (f_rep - bond_order[e] * f_att);
  atomicAdd(&out[d], V);
}

extern "C" void kernel_launch(void* const* d_in, const int* in_sizes, int n_in,
                              void* d_out, int out_size, void* d_ws,
                              size_t ws_size, hipStream_t stream) {
  const float* nf   = (const float*)d_in[0];
  const float* bo   = (const float*)d_in[1];
  const float* bl   = (const float*)d_in[2];
  const int*   src  = (const int*)d_in[3];
  const int*   dst  = (const int*)d_in[4];
  const float* Wsrc = (const float*)d_in[5];
  const float* bsrc = (const float*)d_in[6];
  const float* Wdst = (const float*)d_in[7];
  float* out = (float*)d_out;

  const int n_nodes = out_size;              // 100000
  const int n_edges = in_sizes[1];           // 3200000

  float* esrc = (float*)d_ws;                      // [n_nodes*4]
  float* edst = esrc + (size_t)n_nodes * 4;        // [n_nodes*4]

  // 1) node projections: one wave per node, 4 waves (256 thr) per block
  {
    const int waves_per_block = 256 / 64;
    const int blocks = (n_nodes + waves_per_block - 1) / waves_per_block;
    node_proj_kernel<<<blocks, 256, 0, stream>>>(nf, Wsrc, bsrc, Wdst, esrc,
                                                 edst, n_nodes);
  }

  // 2) zero the output accumulator (harness does NOT re-zero between replays)
  hipMemsetAsync(d_out, 0, (size_t)out_size * sizeof(float), stream);

  // 3) per-edge potential + atomic scatter-sum
  {
    const int blocks = (n_edges + 255) / 256;
    edge_kernel<<<blocks, 256, 0, stream>>>(bo, bl, src, dst, esrc, edst, out,
                                            n_edges);
  }
}

// Round 2
// 168.451 us; speedup vs baseline: 1.1547x; 1.1547x over previous
//
#include <hip/hip_runtime.h>
#include <math.h>

// BondOrderInteraction.
// Node stage: P[n*8+0..3] = exp(NF@W_src + b_src), P[n*8+4..7] = exp(NF@W_dst)
// Edge stage: params = P_src[s] * P_dst[d]; V = cutoff(r)*(p0*e^{-p1 r} - bo*p2*e^{-p3 r})
// scatter-add into out[dst].
//
// Inputs: 0 nf[N,256] f32, 1 bond_order[E] f32, 2 bondlength[E] f32,
//         3 src[E] i32, 4 dst[E] i32, 5 W_src[256,4], 6 b_src[4], 7 W_dst[256,4]
// Output: [N] f32

#define F_IN 256

// ---------------- kernel 1: per-node projections, exp'd -------------------
// One wave handles 4 nodes. Lane i covers features [4i,4i+4). Reduce of the
// 8 per-lane partial sums uses a value-splitting butterfly: 7 shuffles to get
// one output per lane-group-of-8, then 3 broadcast-levels. 10 shuffles/node.
__global__ __launch_bounds__(256) void node_proj_kernel(
    const float* __restrict__ nf,
    const float* __restrict__ Wsrc,
    const float* __restrict__ bsrc,
    const float* __restrict__ Wdst,
    float* __restrict__ P,
    int n_nodes) {
  const int wave = (blockIdx.x * blockDim.x + threadIdx.x) >> 6;
  const int lane = threadIdx.x & 63;
  const int node0 = wave * 4;
  if (node0 >= n_nodes) return;
  const int nm = min(4, n_nodes - node0);

  // weight columns for this lane's 4 features (L1/L2-resident, broadcast-ish)
  float4 ws[4], wd[4];
#pragma unroll
  for (int t = 0; t < 4; ++t) {
    ws[t] = *reinterpret_cast<const float4*>(Wsrc + (lane * 4 + t) * 4);
    wd[t] = *reinterpret_cast<const float4*>(Wdst + (lane * 4 + t) * 4);
  }

  float4 f[4];
#pragma unroll
  for (int m = 0; m < 4; ++m) {
    const int node = node0 + (m < nm ? m : 0);
    f[m] = *reinterpret_cast<const float4*>(nf + (size_t)node * F_IN + lane * 4);
  }

  // which output this lane ends up holding after the split-tree
  const int o = (lane & 1) * 4 + ((lane >> 1) & 1) * 2 + ((lane >> 2) & 1);
  const bool b1 = lane & 1, b2 = lane & 2, b4 = lane & 4;

#pragma unroll
  for (int m = 0; m < 4; ++m) {
    float a[8] = {0.f, 0.f, 0.f, 0.f, 0.f, 0.f, 0.f, 0.f};
#pragma unroll
    for (int t = 0; t < 4; ++t) {
      const float fv = (&f[m].x)[t];
      a[0] += fv * ws[t].x; a[1] += fv * ws[t].y;
      a[2] += fv * ws[t].z; a[3] += fv * ws[t].w;
      a[4] += fv * wd[t].x; a[5] += fv * wd[t].y;
      a[6] += fv * wd[t].z; a[7] += fv * wd[t].w;
    }

    // level 1 (xor 1): even lanes keep a[0..3], odd keep a[4..7]
    float s0 = b1 ? a[0] : a[4], s1 = b1 ? a[1] : a[5];
    float s2 = b1 ? a[2] : a[6], s3 = b1 ? a[3] : a[7];
    float r0 = __shfl_xor(s0, 1, 64), r1 = __shfl_xor(s1, 1, 64);
    float r2 = __shfl_xor(s2, 1, 64), r3 = __shfl_xor(s3, 1, 64);
    a[0] = (b1 ? a[4] : a[0]) + r0;
    a[1] = (b1 ? a[5] : a[1]) + r1;
    a[2] = (b1 ? a[6] : a[2]) + r2;
    a[3] = (b1 ? a[7] : a[3]) + r3;
    // level 2 (xor 2): keep a[0..1] / a[2..3]
    s0 = b2 ? a[0] : a[2]; s1 = b2 ? a[1] : a[3];
    r0 = __shfl_xor(s0, 2, 64); r1 = __shfl_xor(s1, 2, 64);
    a[0] = (b2 ? a[2] : a[0]) + r0;
    a[1] = (b2 ? a[3] : a[1]) + r1;
    // level 3 (xor 4): keep a[0] / a[1]
    s0 = b4 ? a[0] : a[1];
    r0 = __shfl_xor(s0, 4, 64);
    float v = (b4 ? a[1] : a[0]) + r0;
    // levels 4..6: plain butterfly on the single value
    v += __shfl_xor(v, 8, 64);
    v += __shfl_xor(v, 16, 64);
    v += __shfl_xor(v, 32, 64);

    if (m < nm && lane < 8) {
      const float bias = (o < 4) ? bsrc[o] : 0.0f;
      P[(size_t)(node0 + m) * 8 + o] = __expf(v + bias);
    }
  }
}

// ---------------- kernel 2: per-edge potential + scatter-add ----------------
// 4 edges per thread: coalesced float4/int4 stream loads, 8 independent
// gathers in flight, predicated on r < 4 (cutoff == 0 beyond).
__global__ __launch_bounds__(256) void edge_kernel(
    const float* __restrict__ bond_order,
    const float* __restrict__ bondlength,
    const int* __restrict__ src,
    const int* __restrict__ dst,
    const float* __restrict__ P,
    float* __restrict__ out,
    int n_edges) {
  const long long base = (long long)(blockIdx.x * blockDim.x + threadIdx.x) * 4;
  if (base >= n_edges) return;

  float rr[4], bb[4];
  int ss[4], dd[4];
  const int rem = (int)(((long long)n_edges - base) < 4 ? (n_edges - base) : 4);
  if (rem == 4) {
    const float4 r4 = *reinterpret_cast<const float4*>(bondlength + base);
    const float4 b4 = *reinterpret_cast<const float4*>(bond_order + base);
    const int4 s4 = *reinterpret_cast<const int4*>(src + base);
    const int4 d4 = *reinterpret_cast<const int4*>(dst + base);
    rr[0] = r4.x; rr[1] = r4.y; rr[2] = r4.z; rr[3] = r4.w;
    bb[0] = b4.x; bb[1] = b4.y; bb[2] = b4.z; bb[3] = b4.w;
    ss[0] = s4.x; ss[1] = s4.y; ss[2] = s4.z; ss[3] = s4.w;
    dd[0] = d4.x; dd[1] = d4.y; dd[2] = d4.z; dd[3] = d4.w;
  } else {
#pragma unroll
    for (int j = 0; j < 4; ++j) {
      rr[j] = 1.0e9f; bb[j] = 0.f; ss[j] = 0; dd[j] = 0;
    }
    for (int j = 0; j < rem; ++j) {
      rr[j] = bondlength[base + j];
      bb[j] = bond_order[base + j];
      ss[j] = src[base + j];
      dd[j] = dst[base + j];
    }
  }

  float4 ps[4], pd[4];
  bool act[4];
#pragma unroll
  for (int j = 0; j < 4; ++j) {
    act[j] = rr[j] < 4.0f;
    if (act[j]) {
      ps[j] = *reinterpret_cast<const float4*>(P + (size_t)ss[j] * 8);
      pd[j] = *reinterpret_cast<const float4*>(P + (size_t)dd[j] * 8 + 4);
    }
  }

#pragma unroll
  for (int j = 0; j < 4; ++j) {
    if (!act[j]) continue;
    const float r = rr[j];
    const float p0 = ps[j].x * pd[j].x;
    const float p1 = ps[j].y * pd[j].y;
    const float p2 = ps[j].z * pd[j].z;
    const float p3 = ps[j].w * pd[j].w;
    const float f_rep = p0 * __expf(-p1 * r);
    const float f_att = p2 * __expf(-p3 * r);
    float c = 1.0f;
    if (r > 3.8f) {
      c = 0.5f - 0.5f * __sinf((float)M_PI * (r - 3.9f) * 5.0f);
    }
    atomicAdd(&out[dd[j]], c * (f_rep - bb[j] * f_att));
  }
}

extern "C" void kernel_launch(void* const* d_in, const int* in_sizes, int n_in,
                              void* d_out, int out_size, void* d_ws,
                              size_t ws_size, hipStream_t stream) {
  const float* nf   = (const float*)d_in[0];
  const float* bo   = (const float*)d_in[1];
  const float* bl   = (const float*)d_in[2];
  const int*   src  = (const int*)d_in[3];
  const int*   dst  = (const int*)d_in[4];
  const float* Wsrc = (const float*)d_in[5];
  const float* bsrc = (const float*)d_in[6];
  const float* Wdst = (const float*)d_in[7];
  float* out = (float*)d_out;

  const int n_nodes = out_size;     // 100000
  const int n_edges = in_sizes[1];  // 3200000

  float* P = (float*)d_ws;  // [n_nodes * 8] interleaved node params (exp'd)

  // 1) node projections: 4 nodes/wave, 4 waves/block -> 16 nodes/block
  {
    const int nodes_per_block = 16;
    const int blocks = (n_nodes + nodes_per_block - 1) / nodes_per_block;
    node_proj_kernel<<<blocks, 256, 0, stream>>>(nf, Wsrc, bsrc, Wdst, P,
                                                 n_nodes);
  }

  // 2) zero the output accumulator (harness poisons, never re-zeros)
  hipMemsetAsync(d_out, 0, (size_t)out_size * sizeof(float), stream);

  // 3) per-edge potential + atomic scatter-sum, 4 edges/thread
  {
    const long long threads = ((long long)n_edges + 3) / 4;
    const int blocks = (int)((threads + 255) / 256);
    edge_kernel<<<blocks, 256, 0, stream>>>(bo, bl, src, dst, P, out, n_edges);
  }
}